// Round 17
// baseline (208.324 us; speedup 1.0000x reference)
//
#include <hip/hip_runtime.h>

#define C 128
#define MAXNB 1024
#define RCAP 4096   // max bucket edges covered by staging reads
#define HCAP 2048   // max edges per half-bucket in LDS
typedef unsigned int uint;
typedef unsigned short ushort;
typedef __attribute__((ext_vector_type(4))) float f32x4;
typedef __attribute__((ext_vector_type(8))) short bf16x8;

__device__ __forceinline__ float blo(uint u) { return __uint_as_float(u << 16); }
__device__ __forceinline__ float bhi(uint u) { return __uint_as_float(u & 0xFFFF0000u); }
// pack two f32 -> (bf16(LO) | bf16(HI)<<16), round-half-up
#define PACKBF(LO, HI) __builtin_amdgcn_perm(__float_as_uint(HI) + 0x8000u, \
                                             __float_as_uint(LO) + 0x8000u, 0x07060302u)

// ---------------- A1: per-block bucket histogram (16384 edges/block) ----------------
__global__ __launch_bounds__(512) void k_hist(const int* __restrict__ col,
                                              int* __restrict__ counts,
                                              int nE, int NB, int NBLK) {
    __shared__ int hist[MAXNB];
    const int t = threadIdx.x, blk = blockIdx.x;
    for (int i = t; i < NB; i += 512) hist[i] = 0;
    __syncthreads();
    const int base = blk * 16384;
    for (int k = 0; k < 32; ++k) {
        int e = base + k * 512 + t;
        if (e < nE) atomicAdd(&hist[col[e] >> 7], 1);
    }
    __syncthreads();
    for (int i = t; i < NB; i += 512) counts[i * NBLK + blk] = hist[i];
}

// ---------------- exclusive scan of counts[scanN], 2 kernels ----------------
// global_prefix(i) = counts[i] + bsum[i>>8]  (consumers fold it in).
__global__ __launch_bounds__(256) void k_scan1(int* __restrict__ counts,
                                               int* __restrict__ bsum, int scanN) {
    __shared__ int s[256];
    int t = threadIdx.x;
    int i = blockIdx.x * 256 + t;
    int v = (i < scanN) ? counts[i] : 0;
    s[t] = v;
    __syncthreads();
    for (int d = 1; d < 256; d <<= 1) {
        int a = (t >= d) ? s[t - d] : 0;
        __syncthreads();
        s[t] += a;
        __syncthreads();
    }
    if (i < scanN) counts[i] = s[t] - v;
    if (t == 255) bsum[blockIdx.x] = s[255];
}

__global__ __launch_bounds__(256) void k_scan2(int* __restrict__ bsum, int nb) {
    __shared__ int s[256];
    __shared__ int carry;
    int t = threadIdx.x;
    if (t == 0) carry = 0;
    __syncthreads();
    int nch = (nb + 255) / 256;
    for (int c = 0; c < nch; ++c) {
        int i = c * 256 + t;
        int v = (i < nb) ? bsum[i] : 0;
        s[t] = v;
        __syncthreads();
        for (int d = 1; d < 256; d <<= 1) {
            int a = (t >= d) ? s[t - d] : 0;
            __syncthreads();
            s[t] += a;
            __syncthreads();
        }
        int cb = carry;
        if (i < nb) bsum[i] = s[t] - v + cb;
        int tot = s[255];
        __syncthreads();
        if (t == 0) carry = cb + tot;
        __syncthreads();
    }
}

// ---------------- A2: bin edges into bucket regions (16384 edges/block) ----------------
__global__ __launch_bounds__(512) void k_scatter(const int* __restrict__ ei,
                                                 const float* __restrict__ ew,
                                                 const int* __restrict__ counts,
                                                 const int* __restrict__ bsum,
                                                 int2* __restrict__ ev2,
                                                 int nE, int NB, int NBLK) {
    __shared__ int base_l[MAXNB];
    __shared__ int cnt_l[MAXNB];
    const int t = threadIdx.x, blk = blockIdx.x;
    for (int i = t; i < NB; i += 512) {
        int idx = i * NBLK + blk;
        base_l[i] = counts[idx] + bsum[idx >> 8];
        cnt_l[i] = 0;
    }
    __syncthreads();
    const int base = blk * 16384;
    for (int k = 0; k < 32; ++k) {
        int e = base + k * 512 + t;
        if (e >= nE) continue;
        int c = ei[nE + e];
        int row = ei[e];
        int b = c >> 7;
        int pos = base_l[b] + atomicAdd(&cnt_l[b], 1);
        ev2[pos] = make_int2(((c & 127) << 25) | row, __float_as_int(ew[e]));
    }
}

// ---------------- B1: per-bucket degree -> dis (single pass over ev2) ----------------
__global__ __launch_bounds__(256) void k_deg(const int2* __restrict__ ev2,
                                             const int* __restrict__ counts,
                                             const int* __restrict__ bsum,
                                             float* __restrict__ dis,
                                             int n, int nE, int NB, int NBLK) {
    __shared__ float wsum[128];
    __shared__ int seg[2];
    const int t = threadIdx.x, b = blockIdx.x;
    if (t < 128) wsum[t] = 0.f;
    if (t == 0) { int i0 = b * NBLK; seg[0] = counts[i0] + bsum[i0 >> 8]; }
    if (t == 1) { int i1 = (b + 1) * NBLK; seg[1] = (b + 1 < NB) ? counts[i1] + bsum[i1 >> 8] : nE; }
    __syncthreads();
    const int s = seg[0], e = seg[1];
    for (int i = s + t; i < e; i += 256) {
        int2 E = ev2[i];
        atomicAdd(&wsum[(uint)E.x >> 25], __int_as_float(E.y));
    }
    __syncthreads();
    int col = (b << 7) + t;
    if (t < 128 && col < n) dis[col] = rsqrtf(1.0f + wsum[t]);
}

// ---------------- xb' = bf16(dis[r]*x[r]); tail blocks: WbT = bf16(W^T) ----------------
__global__ __launch_bounds__(256) void k_cvt(const float4* __restrict__ x4,
                                             const float* __restrict__ dis,
                                             ushort4* __restrict__ xb4,
                                             const float* __restrict__ W,
                                             ushort* __restrict__ WbT,
                                             long total4, int cvtB) {
    if ((int)blockIdx.x >= cvtB) {
        int idx = ((int)blockIdx.x - cvtB) * 256 + threadIdx.x;   // 16384 total
        int k = idx >> 7, o = idx & 127;
        uint u = __float_as_uint(W[idx]);
        WbT[o * 128 + k] = (ushort)((u + 0x7FFFu + ((u >> 16) & 1u)) >> 16);
        return;
    }
    long i = (long)blockIdx.x * 256 + threadIdx.x;
    if (i >= total4) return;
    float d = dis[i >> 5];
    float4 v = x4[i];
    ushort4 r;
#define RNE(OUT, F)                                                     \
    {                                                                   \
        uint u = __float_as_uint((F) * d);                              \
        OUT = (ushort)((u + 0x7FFFu + ((u >> 16) & 1u)) >> 16);         \
    }
    RNE(r.x, v.x) RNE(r.y, v.y) RNE(r.z, v.z) RNE(r.w, v.w)
#undef RNE
    xb4[i] = r;
}

// ---------------- B2: per-HALF-bucket sort (LDS) + segment aggregation ----------------
// Block = 64 cols (half of a 128-col bucket). Phase A: stage the full bucket's
// edges, keep the half's, count/scan/ticket -> col-sorted LDS list (16 KB).
// Phase B: 16 groups x 4 cols, gather (same proven inner loop).
__global__ __launch_bounds__(256) void k_segagg(const ushort* __restrict__ xb,
                                                const int2* __restrict__ ev2,
                                                const int* __restrict__ counts,
                                                const int* __restrict__ bsum,
                                                const float* __restrict__ dis,
                                                ushort* __restrict__ aggb,
                                                int n, int nE, int NB, int NBLK) {
    __shared__ int2 se[HCAP];       // 16 KB sorted edges (this half only)
    __shared__ int cnt[64];
    __shared__ int sc[64];
    __shared__ int cur[64];
    __shared__ int seg[2];
    const int t = threadIdx.x;
    const int b = blockIdx.x >> 1;      // bucket
    const int half = blockIdx.x & 1;    // 0: cols 0-63, 1: cols 64-127
    if (t < 64) cnt[t] = 0;
    if (t == 0) { int i0 = b * NBLK; seg[0] = counts[i0] + bsum[i0 >> 8]; }
    if (t == 1) { int i1 = (b + 1) * NBLK; seg[1] = (b + 1 < NB) ? counts[i1] + bsum[i1 >> 8] : nE; }
    __syncthreads();
    const int s = seg[0], e = seg[1];
    const int m = e - s;

    int2 held[16];
    if (m <= RCAP) {
        // stage full bucket, count only this half's edges
#pragma unroll
        for (int r = 0; r < 16; ++r) {
            int idx = r * 256 + t;
            held[r] = make_int2(half << 31, 0);   // sentinel: wrong half when idx>=m
            if (idx < m) {
                held[r] = ev2[s + idx];
                int cl = (uint)held[r].x >> 25;
                if ((cl >> 6) == half) atomicAdd(&cnt[cl & 63], 1);
            }
        }
        __syncthreads();
        if (t < 64) sc[t] = cnt[t];
        __syncthreads();
        for (int d = 1; d < 64; d <<= 1) {
            int v = 0;
            if (t < 64 && t >= d) v = sc[t - d];
            __syncthreads();
            if (t < 64) sc[t] += v;
            __syncthreads();
        }
        if (t < 64) cur[t] = sc[t] - cnt[t];   // local exclusive offset
        __syncthreads();
    }
    const bool fits = (m <= RCAP) && (sc[63] <= HCAP);   // block-uniform
    if (fits) {
#pragma unroll
        for (int r = 0; r < 16; ++r) {
            int idx = r * 256 + t;
            if (idx < m) {
                int cl = (uint)held[r].x >> 25;
                if ((cl >> 6) == half) {
                    int pos = atomicAdd(&cur[cl & 63], 1);
                    se[pos] = make_int2(held[r].x & 0x1FFFFFF, held[r].y);
                }
            }
        }
    }
    __syncthreads();

    // ---- phase B: 16 groups x 4 cols, no barriers below ----
    const int lane = t & 15;
    const int g = t >> 4;

#define EDGE(E, V)                                                        \
    {                                                                     \
        float nw = __int_as_float(E.y);                                   \
        acc[0] = fmaf(nw, blo(V.x), acc[0]);                              \
        acc[1] = fmaf(nw, bhi(V.x), acc[1]);                              \
        acc[2] = fmaf(nw, blo(V.y), acc[2]);                              \
        acc[3] = fmaf(nw, bhi(V.y), acc[3]);                              \
        acc[4] = fmaf(nw, blo(V.z), acc[4]);                              \
        acc[5] = fmaf(nw, bhi(V.z), acc[5]);                              \
        acc[6] = fmaf(nw, blo(V.w), acc[6]);                              \
        acc[7] = fmaf(nw, bhi(V.w), acc[7]);                              \
    }
#define GATH(K) uint4 v##K = *(const uint4*)(xb + (size_t)e##K.x * C + lane * 8);

    for (int cc = 0; cc < 4; ++cc) {
        const int cl = g * 4 + cc;                    // 0..63 local
        const int col = (b << 7) + (half << 6) + cl;  // global col
        if (col >= n) continue;

        uint4 sv = *(const uint4*)(xb + (size_t)col * C + lane * 8);
        float acc[8] = {blo(sv.x), bhi(sv.x), blo(sv.y), bhi(sv.y),
                        blo(sv.z), bhi(sv.z), blo(sv.w), bhi(sv.w)};

        if (fits) {
            int i = sc[cl] - cnt[cl];
            const int end2 = sc[cl];
            for (; i + 8 <= end2; i += 8) {
                int2 e0 = se[i],     e1 = se[i + 1], e2 = se[i + 2], e3 = se[i + 3];
                int2 e4 = se[i + 4], e5 = se[i + 5], e6 = se[i + 6], e7 = se[i + 7];
                GATH(0) GATH(1) GATH(2) GATH(3) GATH(4) GATH(5) GATH(6) GATH(7)
                EDGE(e0, v0) EDGE(e1, v1) EDGE(e2, v2) EDGE(e3, v3)
                EDGE(e4, v4) EDGE(e5, v5) EDGE(e6, v6) EDGE(e7, v7)
            }
            for (; i + 2 <= end2; i += 2) {
                int2 e0 = se[i], e1 = se[i + 1];
                GATH(0) GATH(1)
                EDGE(e0, v0) EDGE(e1, v1)
            }
            if (i < end2) {
                int2 e0 = se[i];
                GATH(0)
                EDGE(e0, v0)
            }
        } else {
            // overflow fallback (statistically never): filter-scan the bucket range
            const int clg = (half << 6) + cl;
            for (int i = s; i < e; ++i) {
                int2 E = ev2[i];
                if ((int)((uint)E.x >> 25) == clg) {
                    int2 e0 = make_int2(E.x & 0x1FFFFFF, E.y);
                    GATH(0)
                    EDGE(e0, v0)
                }
            }
        }

        float d = dis[col];
        uint4 r;
        r.x = PACKBF(d * acc[0], d * acc[1]);
        r.y = PACKBF(d * acc[2], d * acc[3]);
        r.z = PACKBF(d * acc[4], d * acc[5]);
        r.w = PACKBF(d * acc[6], d * acc[7]);
        *(uint4*)(aggb + (size_t)col * C + lane * 8) = r;
    }
#undef GATH
#undef EDGE
}

// ---------------- MFMA GEMM: outb = bf16(aggb @ W) ----------------
__global__ __launch_bounds__(256, 4) void k_gemm(const ushort* __restrict__ aggb,
                                                 ushort* __restrict__ outb,
                                                 const ushort* __restrict__ WbT,
                                                 int n) {
    const int t = threadIdx.x;
    const int lane = t & 63;
    const int wv = t >> 6;
    const int lr = lane & 15;
    const int lk = lane >> 4;
    const long m = (long)blockIdx.x * 64 + wv * 16 + lr;
    const bool inr = m < (long)n;

    bf16x8 b0, b1, b2, b3;
    if (inr) {
        const bf16x8* p = (const bf16x8*)(aggb + (size_t)m * C + lk * 8);
        b0 = p[0];
        b1 = p[4];
        b2 = p[8];
        b3 = p[12];
    } else {
        b0 = b1 = b2 = b3 = (bf16x8){0, 0, 0, 0, 0, 0, 0, 0};
    }

    f32x4 acc[8];
#pragma unroll
    for (int ot = 0; ot < 8; ++ot) acc[ot] = (f32x4){0.f, 0.f, 0.f, 0.f};

#pragma unroll 2
    for (int ot = 0; ot < 8; ++ot) {
        const ushort* wp = WbT + (ot * 16 + lr) * 128 + lk * 8;
        bf16x8 a0 = *(const bf16x8*)(wp);
        bf16x8 a1 = *(const bf16x8*)(wp + 32);
        bf16x8 a2 = *(const bf16x8*)(wp + 64);
        bf16x8 a3 = *(const bf16x8*)(wp + 96);
        acc[ot] = __builtin_amdgcn_mfma_f32_16x16x32_bf16(a0, b0, acc[ot], 0, 0, 0);
        acc[ot] = __builtin_amdgcn_mfma_f32_16x16x32_bf16(a1, b1, acc[ot], 0, 0, 0);
        acc[ot] = __builtin_amdgcn_mfma_f32_16x16x32_bf16(a2, b2, acc[ot], 0, 0, 0);
        acc[ot] = __builtin_amdgcn_mfma_f32_16x16x32_bf16(a3, b3, acc[ot], 0, 0, 0);
    }

    if (inr) {
        ushort* orow = outb + (size_t)m * C + lk * 4;
#pragma unroll
        for (int ot = 0; ot < 8; ++ot) {
            uint2 r;
            r.x = PACKBF(acc[ot][0], acc[ot][1]);
            r.y = PACKBF(acc[ot][2], acc[ot][3]);
            *(uint2*)(orow + ot * 16) = r;
        }
    }
}

// ---------------- BN stats from bf16 outb: per-block partials ----------------
__global__ __launch_bounds__(1024) void k_stats(const uint4* __restrict__ ob4,
                                                float* __restrict__ part, int n) {
    const int t = threadIdx.x;
    const int cg = t & 15;
    const int rl = t >> 4;
    float s[8] = {0, 0, 0, 0, 0, 0, 0, 0};
    float q[8] = {0, 0, 0, 0, 0, 0, 0, 0};
    for (int r = blockIdx.x * 64 + rl; r < n; r += gridDim.x * 64) {
        uint4 v = ob4[(size_t)r * 16 + cg];
        float f0 = blo(v.x), f1 = bhi(v.x), f2 = blo(v.y), f3 = bhi(v.y);
        float f4 = blo(v.z), f5 = bhi(v.z), f6 = blo(v.w), f7 = bhi(v.w);
        s[0] += f0; q[0] = fmaf(f0, f0, q[0]);
        s[1] += f1; q[1] = fmaf(f1, f1, q[1]);
        s[2] += f2; q[2] = fmaf(f2, f2, q[2]);
        s[3] += f3; q[3] = fmaf(f3, f3, q[3]);
        s[4] += f4; q[4] = fmaf(f4, f4, q[4]);
        s[5] += f5; q[5] = fmaf(f5, f5, q[5]);
        s[6] += f6; q[6] = fmaf(f6, f6, q[6]);
        s[7] += f7; q[7] = fmaf(f7, f7, q[7]);
    }
#pragma unroll
    for (int j = 0; j < 8; ++j) {
        s[j] += __shfl_xor(s[j], 16); s[j] += __shfl_xor(s[j], 32);
        q[j] += __shfl_xor(q[j], 16); q[j] += __shfl_xor(q[j], 32);
    }
    __shared__ float lds_s[16][128];
    __shared__ float lds_q[16][128];
    const int wvi = t >> 6;
    if ((t & 63) < 16) {
#pragma unroll
        for (int j = 0; j < 8; ++j) {
            lds_s[wvi][cg * 8 + j] = s[j];
            lds_q[wvi][cg * 8 + j] = q[j];
        }
    }
    __syncthreads();
    if (t < 128) {
        float ps = 0.f;
#pragma unroll
        for (int w = 0; w < 16; ++w) ps += lds_s[w][t];
        part[(size_t)blockIdx.x * 256 + t] = ps;
    } else if (t < 256) {
        int c = t - 128;
        float pq = 0.f;
#pragma unroll
        for (int w = 0; w < 16; ++w) pq += lds_q[w][c];
        part[(size_t)blockIdx.x * 256 + t] = pq;
    }
}

__global__ __launch_bounds__(256) void k_finish(const float* __restrict__ part,
                                                float* __restrict__ sums, int nblk) {
    int t = threadIdx.x;
    float s = 0.f;
    for (int b = blockIdx.x; b < nblk; b += gridDim.x) s += part[(size_t)b * 256 + t];
    atomicAdd(&sums[t], s);
}

// ---------------- BN apply + ReLU: outb (bf16) -> out (f32) ----------------
__global__ __launch_bounds__(256) void k_apply(const uint4* __restrict__ ob4,
                                               float* __restrict__ out,
                                               const float* __restrict__ sums,
                                               const float* __restrict__ gamma,
                                               const float* __restrict__ beta,
                                               int n) {
    size_t idx = (size_t)blockIdx.x * 256 + threadIdx.x;   // uint4 index (8 bf16)
    size_t total = (size_t)n * 16;
    if (idx >= total) return;
    int cg = (int)(idx & 15);
    int c0 = cg * 8;
    float inv_n = 1.0f / (float)n;
    uint4 v = ob4[idx];
    float f[8] = {blo(v.x), bhi(v.x), blo(v.y), bhi(v.y),
                  blo(v.z), bhi(v.z), blo(v.w), bhi(v.w)};
    float4 r0, r1;
#define BN1(OUT, J)                                                        \
    {                                                                      \
        float mean = sums[c0 + J] * inv_n;                                 \
        float var  = fmaxf(sums[C + c0 + J] * inv_n - mean * mean, 0.f);   \
        float sc   = rsqrtf(var + 1e-5f) * gamma[c0 + J];                  \
        OUT = fmaxf(fmaf(f[J] - mean, sc, beta[c0 + J]), 0.f);             \
    }
    BN1(r0.x, 0) BN1(r0.y, 1) BN1(r0.z, 2) BN1(r0.w, 3)
    BN1(r1.x, 4) BN1(r1.y, 5) BN1(r1.z, 6) BN1(r1.w, 7)
#undef BN1
    float4* orow = (float4*)(out + (idx >> 4) * C + c0);
    orow[0] = r0;
    orow[1] = r1;
}

extern "C" void kernel_launch(void* const* d_in, const int* in_sizes, int n_in,
                              void* d_out, int out_size, void* d_ws, size_t ws_size,
                              hipStream_t stream) {
    const float* x     = (const float*)d_in[0];
    const int*   ei    = (const int*)d_in[1];   // [2, E]: row = ei[e], col = ei[E+e]
    const float* ew    = (const float*)d_in[2];
    const float* W     = (const float*)d_in[3];
    const float* gamma = (const float*)d_in[4];
    const float* beta  = (const float*)d_in[5];

    const int n  = in_sizes[0] / C;
    const int nE = in_sizes[2];

    const int NB    = (n + 127) >> 7;          // 128-col buckets
    const int NBLK  = (nE + 16383) / 16384;    // hist/scatter blocks
    const int scanN = NB * NBLK;
    const int scanB = (scanN + 255) / 256;
    const int SB    = 256;                     // k_stats blocks

    float* out = (float*)d_out;
    char* p = (char*)d_ws;
#define ALLOC(TYPE, NAME, BYTES) \
    TYPE NAME = (TYPE)p; p += ((size_t)(BYTES) + 255) & ~(size_t)255;
    ALLOC(int2*,   ev2,    (size_t)nE * 8)
    ALLOC(ushort*, xb,     (size_t)n * C * 2)
    ALLOC(ushort*, aggb,   (size_t)n * C * 2)
    ALLOC(ushort*, outb,   (size_t)n * C * 2)
    ALLOC(int*,    counts, (size_t)scanN * 4)
    ALLOC(int*,    bsum,   (size_t)scanB * 4)
    ALLOC(float*,  dis,    (size_t)n * 4)
    ALLOC(ushort*, WbT,    32768)
    ALLOC(float*,  sums,   1024)
    ALLOC(float*,  part,   (size_t)SB * 256 * 4)
#undef ALLOC

    const long total4 = (long)n * 32;   // n*C/4 (f32 float4s)
    const long totalb = (long)n * 16;   // n*C/8 (bf16 uint4s)
    const int  cvtB   = (int)((total4 + 255) / 256);

    hipMemsetAsync(sums, 0, 256 * 4, stream);

    k_hist   <<<NBLK, 512, 0, stream>>>(ei + nE, counts, nE, NB, NBLK);
    k_scan1  <<<scanB, 256, 0, stream>>>(counts, bsum, scanN);
    k_scan2  <<<1, 256, 0, stream>>>(bsum, scanB);
    k_scatter<<<NBLK, 512, 0, stream>>>(ei, ew, counts, bsum, ev2, nE, NB, NBLK);
    k_deg    <<<NB, 256, 0, stream>>>(ev2, counts, bsum, dis, n, nE, NB, NBLK);
    k_cvt    <<<cvtB + 64, 256, 0, stream>>>((const float4*)x, dis, (ushort4*)xb, W, WbT, total4, cvtB);
    k_segagg <<<NB * 2, 256, 0, stream>>>(xb, ev2, counts, bsum, dis, aggb, n, nE, NB, NBLK);
    k_gemm   <<<(n + 63) / 64, 256, 0, stream>>>(aggb, outb, WbT, n);
    k_stats  <<<SB, 1024, 0, stream>>>((const uint4*)outb, part, n);
    k_finish <<<16, 256, 0, stream>>>(part, sums, SB);
    k_apply  <<<(int)((totalb + 255) / 256), 256, 0, stream>>>((const uint4*)outb, out, sums, gamma, beta, n);
}

// Round 18
// 194.391 us; speedup vs baseline: 1.0717x; 1.0717x over previous
//
#include <hip/hip_runtime.h>

#define C 128
#define MAXNB 1024
#define CAP 4096
typedef unsigned int uint;
typedef unsigned short ushort;
typedef __attribute__((ext_vector_type(4))) float f32x4;
typedef __attribute__((ext_vector_type(8))) short bf16x8;

__device__ __forceinline__ float blo(uint u) { return __uint_as_float(u << 16); }
__device__ __forceinline__ float bhi(uint u) { return __uint_as_float(u & 0xFFFF0000u); }
// pack two f32 -> (bf16(LO) | bf16(HI)<<16), round-half-up
#define PACKBF(LO, HI) __builtin_amdgcn_perm(__float_as_uint(HI) + 0x8000u, \
                                             __float_as_uint(LO) + 0x8000u, 0x07060302u)

// ---------------- A1: per-block bucket histogram (8192 edges/block) ----------------
__global__ __launch_bounds__(512) void k_hist(const int* __restrict__ col,
                                              int* __restrict__ counts,
                                              int nE, int NB, int NBLK) {
    __shared__ int hist[MAXNB];
    const int t = threadIdx.x, blk = blockIdx.x;
    for (int i = t; i < NB; i += 512) hist[i] = 0;
    __syncthreads();
    const int base = blk * 8192;
    for (int k = 0; k < 16; ++k) {
        int e = base + k * 512 + t;
        if (e < nE) atomicAdd(&hist[col[e] >> 7], 1);
    }
    __syncthreads();
    for (int i = t; i < NB; i += 512) counts[i * NBLK + blk] = hist[i];
}

// ---------------- exclusive scan of counts[scanN], 2 kernels ----------------
// global_prefix(i) = counts[i] + bsum[i>>8]  (consumers fold it in).
__global__ __launch_bounds__(256) void k_scan1(int* __restrict__ counts,
                                               int* __restrict__ bsum, int scanN) {
    __shared__ int s[256];
    int t = threadIdx.x;
    int i = blockIdx.x * 256 + t;
    int v = (i < scanN) ? counts[i] : 0;
    s[t] = v;
    __syncthreads();
    for (int d = 1; d < 256; d <<= 1) {
        int a = (t >= d) ? s[t - d] : 0;
        __syncthreads();
        s[t] += a;
        __syncthreads();
    }
    if (i < scanN) counts[i] = s[t] - v;
    if (t == 255) bsum[blockIdx.x] = s[255];
}

__global__ __launch_bounds__(256) void k_scan2(int* __restrict__ bsum, int nb) {
    __shared__ int s[256];
    __shared__ int carry;
    int t = threadIdx.x;
    if (t == 0) carry = 0;
    __syncthreads();
    int nch = (nb + 255) / 256;
    for (int c = 0; c < nch; ++c) {
        int i = c * 256 + t;
        int v = (i < nb) ? bsum[i] : 0;
        s[t] = v;
        __syncthreads();
        for (int d = 1; d < 256; d <<= 1) {
            int a = (t >= d) ? s[t - d] : 0;
            __syncthreads();
            s[t] += a;
            __syncthreads();
        }
        int cb = carry;
        if (i < nb) bsum[i] = s[t] - v + cb;
        int tot = s[255];
        __syncthreads();
        if (t == 0) carry = cb + tot;
        __syncthreads();
    }
}

// ---------------- A2: bin edges into bucket regions (8192 edges/block) ----------------
__global__ __launch_bounds__(512) void k_scatter(const int* __restrict__ ei,
                                                 const float* __restrict__ ew,
                                                 const int* __restrict__ counts,
                                                 const int* __restrict__ bsum,
                                                 int2* __restrict__ ev2,
                                                 int nE, int NB, int NBLK) {
    __shared__ int base_l[MAXNB];
    __shared__ int cnt_l[MAXNB];
    const int t = threadIdx.x, blk = blockIdx.x;
    for (int i = t; i < NB; i += 512) {
        int idx = i * NBLK + blk;
        base_l[i] = counts[idx] + bsum[idx >> 8];
        cnt_l[i] = 0;
    }
    __syncthreads();
    const int base = blk * 8192;
    for (int k = 0; k < 16; ++k) {
        int e = base + k * 512 + t;
        if (e >= nE) continue;
        int c = ei[nE + e];
        int row = ei[e];
        int b = c >> 7;
        int pos = base_l[b] + atomicAdd(&cnt_l[b], 1);
        ev2[pos] = make_int2(((c & 127) << 25) | row, __float_as_int(ew[e]));
    }
}

// ---------------- B1: per-bucket degree -> dis (single pass over ev2) ----------------
__global__ __launch_bounds__(256) void k_deg(const int2* __restrict__ ev2,
                                             const int* __restrict__ counts,
                                             const int* __restrict__ bsum,
                                             float* __restrict__ dis,
                                             int n, int nE, int NB, int NBLK) {
    __shared__ float wsum[128];
    __shared__ int seg[2];
    const int t = threadIdx.x, b = blockIdx.x;
    if (t < 128) wsum[t] = 0.f;
    if (t == 0) { int i0 = b * NBLK; seg[0] = counts[i0] + bsum[i0 >> 8]; }
    if (t == 1) { int i1 = (b + 1) * NBLK; seg[1] = (b + 1 < NB) ? counts[i1] + bsum[i1 >> 8] : nE; }
    __syncthreads();
    const int s = seg[0], e = seg[1];
    for (int i = s + t; i < e; i += 256) {
        int2 E = ev2[i];
        atomicAdd(&wsum[(uint)E.x >> 25], __int_as_float(E.y));
    }
    __syncthreads();
    int col = (b << 7) + t;
    if (t < 128 && col < n) dis[col] = rsqrtf(1.0f + wsum[t]);
}

// ---------------- xb' = bf16(dis[r]*x[r]); tail blocks: WbT = bf16(W^T) ----------------
__global__ __launch_bounds__(256) void k_cvt(const float4* __restrict__ x4,
                                             const float* __restrict__ dis,
                                             ushort4* __restrict__ xb4,
                                             const float* __restrict__ W,
                                             ushort* __restrict__ WbT,
                                             long total4, int cvtB) {
    if ((int)blockIdx.x >= cvtB) {
        int idx = ((int)blockIdx.x - cvtB) * 256 + threadIdx.x;   // 16384 total
        int k = idx >> 7, o = idx & 127;
        uint u = __float_as_uint(W[idx]);
        WbT[o * 128 + k] = (ushort)((u + 0x7FFFu + ((u >> 16) & 1u)) >> 16);
        return;
    }
    long i = (long)blockIdx.x * 256 + threadIdx.x;
    if (i >= total4) return;
    float d = dis[i >> 5];
    float4 v = x4[i];
    ushort4 r;
#define RNE(OUT, F)                                                     \
    {                                                                   \
        uint u = __float_as_uint((F) * d);                              \
        OUT = (ushort)((u + 0x7FFFu + ((u >> 16) & 1u)) >> 16);         \
    }
    RNE(r.x, v.x) RNE(r.y, v.y) RNE(r.z, v.z) RNE(r.w, v.w)
#undef RNE
    xb4[i] = r;
}

// ---------------- B2: fused per-bucket sort (LDS) + segment aggregation ----------------
// Block = one 128-col bucket. Phase A: stage bucket edges in registers, count per
// col, scan, ticket -> col-sorted LDS list. Phase B: 16 groups x 8 cols, gather.
__global__ __launch_bounds__(256) void k_segagg(const ushort* __restrict__ xb,
                                                const int2* __restrict__ ev2,
                                                const int* __restrict__ counts,
                                                const int* __restrict__ bsum,
                                                const float* __restrict__ dis,
                                                ushort* __restrict__ aggb,
                                                int n, int nE, int NB, int NBLK) {
    __shared__ int2 se[CAP];        // 32 KB sorted edges
    __shared__ int cnt[128];
    __shared__ int sc[128];
    __shared__ int cur[128];
    __shared__ int seg[2];
    const int t = threadIdx.x, b = blockIdx.x;
    if (t < 128) cnt[t] = 0;
    if (t == 0) { int i0 = b * NBLK; seg[0] = counts[i0] + bsum[i0 >> 8]; }
    if (t == 1) { int i1 = (b + 1) * NBLK; seg[1] = (b + 1 < NB) ? counts[i1] + bsum[i1 >> 8] : nE; }
    __syncthreads();
    const int s = seg[0], e = seg[1];
    const int m = e - s;
    const bool fits = (m <= CAP);   // block-uniform

    if (fits) {
        int2 held[16];
        // stage + count (fully unrolled -> compile-time indices, no scratch)
#pragma unroll
        for (int r = 0; r < 16; ++r) {
            int idx = r * 256 + t;
            held[r] = make_int2(0, 0);
            if (idx < m) {
                held[r] = ev2[s + idx];
                atomicAdd(&cnt[(uint)held[r].x >> 25], 1);
            }
        }
        __syncthreads();
        if (t < 128) sc[t] = cnt[t];
        __syncthreads();
        for (int d = 1; d < 128; d <<= 1) {
            int v = 0;
            if (t < 128 && t >= d) v = sc[t - d];
            __syncthreads();
            if (t < 128) sc[t] += v;
            __syncthreads();
        }
        if (t < 128) cur[t] = sc[t] - cnt[t];   // local exclusive offset
        __syncthreads();
#pragma unroll
        for (int r = 0; r < 16; ++r) {
            int idx = r * 256 + t;
            if (idx < m) {
                int cl = (uint)held[r].x >> 25;
                int pos = atomicAdd(&cur[cl], 1);
                se[pos] = make_int2(held[r].x & 0x1FFFFFF, held[r].y);
            }
        }
        __syncthreads();
    }

    // ---- phase B: 16 groups x 8 cols, no barriers below ----
    const int lane = t & 15;
    const int g = t >> 4;

#define EDGE(E, V)                                                        \
    {                                                                     \
        float nw = __int_as_float(E.y);                                   \
        acc[0] = fmaf(nw, blo(V.x), acc[0]);                              \
        acc[1] = fmaf(nw, bhi(V.x), acc[1]);                              \
        acc[2] = fmaf(nw, blo(V.y), acc[2]);                              \
        acc[3] = fmaf(nw, bhi(V.y), acc[3]);                              \
        acc[4] = fmaf(nw, blo(V.z), acc[4]);                              \
        acc[5] = fmaf(nw, bhi(V.z), acc[5]);                              \
        acc[6] = fmaf(nw, blo(V.w), acc[6]);                              \
        acc[7] = fmaf(nw, bhi(V.w), acc[7]);                              \
    }
#define GATH(K) uint4 v##K = *(const uint4*)(xb + (size_t)e##K.x * C + lane * 8);

    for (int cc = 0; cc < 8; ++cc) {
        const int cl = g * 8 + cc;
        const int col = (b << 7) + cl;
        if (col >= n) continue;

        uint4 sv = *(const uint4*)(xb + (size_t)col * C + lane * 8);
        float acc[8] = {blo(sv.x), bhi(sv.x), blo(sv.y), bhi(sv.y),
                        blo(sv.z), bhi(sv.z), blo(sv.w), bhi(sv.w)};

        if (fits) {
            int i = sc[cl] - cnt[cl];
            const int end2 = sc[cl];
            for (; i + 8 <= end2; i += 8) {
                int2 e0 = se[i],     e1 = se[i + 1], e2 = se[i + 2], e3 = se[i + 3];
                int2 e4 = se[i + 4], e5 = se[i + 5], e6 = se[i + 6], e7 = se[i + 7];
                GATH(0) GATH(1) GATH(2) GATH(3) GATH(4) GATH(5) GATH(6) GATH(7)
                EDGE(e0, v0) EDGE(e1, v1) EDGE(e2, v2) EDGE(e3, v3)
                EDGE(e4, v4) EDGE(e5, v5) EDGE(e6, v6) EDGE(e7, v7)
            }
            for (; i + 2 <= end2; i += 2) {
                int2 e0 = se[i], e1 = se[i + 1];
                GATH(0) GATH(1)
                EDGE(e0, v0) EDGE(e1, v1)
            }
            if (i < end2) {
                int2 e0 = se[i];
                GATH(0)
                EDGE(e0, v0)
            }
        } else {
            // overflow fallback (statistically never): filter-scan the bucket range
            for (int i = s; i < e; ++i) {
                int2 E = ev2[i];
                if ((int)((uint)E.x >> 25) == cl) {
                    int2 e0 = make_int2(E.x & 0x1FFFFFF, E.y);
                    GATH(0)
                    EDGE(e0, v0)
                }
            }
        }

        float d = dis[col];
        uint4 r;
        r.x = PACKBF(d * acc[0], d * acc[1]);
        r.y = PACKBF(d * acc[2], d * acc[3]);
        r.z = PACKBF(d * acc[4], d * acc[5]);
        r.w = PACKBF(d * acc[6], d * acc[7]);
        *(uint4*)(aggb + (size_t)col * C + lane * 8) = r;
    }
#undef GATH
#undef EDGE
}

// ---------------- MFMA GEMM: outb = bf16(aggb @ W) ----------------
__global__ __launch_bounds__(256, 4) void k_gemm(const ushort* __restrict__ aggb,
                                                 ushort* __restrict__ outb,
                                                 const ushort* __restrict__ WbT,
                                                 int n) {
    const int t = threadIdx.x;
    const int lane = t & 63;
    const int wv = t >> 6;
    const int lr = lane & 15;
    const int lk = lane >> 4;
    const long m = (long)blockIdx.x * 64 + wv * 16 + lr;
    const bool inr = m < (long)n;

    bf16x8 b0, b1, b2, b3;
    if (inr) {
        const bf16x8* p = (const bf16x8*)(aggb + (size_t)m * C + lk * 8);
        b0 = p[0];
        b1 = p[4];
        b2 = p[8];
        b3 = p[12];
    } else {
        b0 = b1 = b2 = b3 = (bf16x8){0, 0, 0, 0, 0, 0, 0, 0};
    }

    f32x4 acc[8];
#pragma unroll
    for (int ot = 0; ot < 8; ++ot) acc[ot] = (f32x4){0.f, 0.f, 0.f, 0.f};

#pragma unroll 2
    for (int ot = 0; ot < 8; ++ot) {
        const ushort* wp = WbT + (ot * 16 + lr) * 128 + lk * 8;
        bf16x8 a0 = *(const bf16x8*)(wp);
        bf16x8 a1 = *(const bf16x8*)(wp + 32);
        bf16x8 a2 = *(const bf16x8*)(wp + 64);
        bf16x8 a3 = *(const bf16x8*)(wp + 96);
        acc[ot] = __builtin_amdgcn_mfma_f32_16x16x32_bf16(a0, b0, acc[ot], 0, 0, 0);
        acc[ot] = __builtin_amdgcn_mfma_f32_16x16x32_bf16(a1, b1, acc[ot], 0, 0, 0);
        acc[ot] = __builtin_amdgcn_mfma_f32_16x16x32_bf16(a2, b2, acc[ot], 0, 0, 0);
        acc[ot] = __builtin_amdgcn_mfma_f32_16x16x32_bf16(a3, b3, acc[ot], 0, 0, 0);
    }

    if (inr) {
        ushort* orow = outb + (size_t)m * C + lk * 4;
#pragma unroll
        for (int ot = 0; ot < 8; ++ot) {
            uint2 r;
            r.x = PACKBF(acc[ot][0], acc[ot][1]);
            r.y = PACKBF(acc[ot][2], acc[ot][3]);
            *(uint2*)(orow + ot * 16) = r;
        }
    }
}

// ---------------- BN stats from bf16 outb: per-block partials ----------------
__global__ __launch_bounds__(1024) void k_stats(const uint4* __restrict__ ob4,
                                                float* __restrict__ part, int n) {
    const int t = threadIdx.x;
    const int cg = t & 15;
    const int rl = t >> 4;
    float s[8] = {0, 0, 0, 0, 0, 0, 0, 0};
    float q[8] = {0, 0, 0, 0, 0, 0, 0, 0};
    for (int r = blockIdx.x * 64 + rl; r < n; r += gridDim.x * 64) {
        uint4 v = ob4[(size_t)r * 16 + cg];
        float f0 = blo(v.x), f1 = bhi(v.x), f2 = blo(v.y), f3 = bhi(v.y);
        float f4 = blo(v.z), f5 = bhi(v.z), f6 = blo(v.w), f7 = bhi(v.w);
        s[0] += f0; q[0] = fmaf(f0, f0, q[0]);
        s[1] += f1; q[1] = fmaf(f1, f1, q[1]);
        s[2] += f2; q[2] = fmaf(f2, f2, q[2]);
        s[3] += f3; q[3] = fmaf(f3, f3, q[3]);
        s[4] += f4; q[4] = fmaf(f4, f4, q[4]);
        s[5] += f5; q[5] = fmaf(f5, f5, q[5]);
        s[6] += f6; q[6] = fmaf(f6, f6, q[6]);
        s[7] += f7; q[7] = fmaf(f7, f7, q[7]);
    }
#pragma unroll
    for (int j = 0; j < 8; ++j) {
        s[j] += __shfl_xor(s[j], 16); s[j] += __shfl_xor(s[j], 32);
        q[j] += __shfl_xor(q[j], 16); q[j] += __shfl_xor(q[j], 32);
    }
    __shared__ float lds_s[16][128];
    __shared__ float lds_q[16][128];
    const int wvi = t >> 6;
    if ((t & 63) < 16) {
#pragma unroll
        for (int j = 0; j < 8; ++j) {
            lds_s[wvi][cg * 8 + j] = s[j];
            lds_q[wvi][cg * 8 + j] = q[j];
        }
    }
    __syncthreads();
    if (t < 128) {
        float ps = 0.f;
#pragma unroll
        for (int w = 0; w < 16; ++w) ps += lds_s[w][t];
        part[(size_t)blockIdx.x * 256 + t] = ps;
    } else if (t < 256) {
        int c = t - 128;
        float pq = 0.f;
#pragma unroll
        for (int w = 0; w < 16; ++w) pq += lds_q[w][c];
        part[(size_t)blockIdx.x * 256 + t] = pq;
    }
}

__global__ __launch_bounds__(256) void k_finish(const float* __restrict__ part,
                                                float* __restrict__ sums, int nblk) {
    int t = threadIdx.x;
    float s = 0.f;
    for (int b = blockIdx.x; b < nblk; b += gridDim.x) s += part[(size_t)b * 256 + t];
    atomicAdd(&sums[t], s);
}

// ---------------- BN apply + ReLU: outb (bf16) -> out (f32) ----------------
__global__ __launch_bounds__(256) void k_apply(const uint4* __restrict__ ob4,
                                               float* __restrict__ out,
                                               const float* __restrict__ sums,
                                               const float* __restrict__ gamma,
                                               const float* __restrict__ beta,
                                               int n) {
    size_t idx = (size_t)blockIdx.x * 256 + threadIdx.x;   // uint4 index (8 bf16)
    size_t total = (size_t)n * 16;
    if (idx >= total) return;
    int cg = (int)(idx & 15);
    int c0 = cg * 8;
    float inv_n = 1.0f / (float)n;
    uint4 v = ob4[idx];
    float f[8] = {blo(v.x), bhi(v.x), blo(v.y), bhi(v.y),
                  blo(v.z), bhi(v.z), blo(v.w), bhi(v.w)};
    float4 r0, r1;
#define BN1(OUT, J)                                                        \
    {                                                                      \
        float mean = sums[c0 + J] * inv_n;                                 \
        float var  = fmaxf(sums[C + c0 + J] * inv_n - mean * mean, 0.f);   \
        float sc   = rsqrtf(var + 1e-5f) * gamma[c0 + J];                  \
        OUT = fmaxf(fmaf(f[J] - mean, sc, beta[c0 + J]), 0.f);             \
    }
    BN1(r0.x, 0) BN1(r0.y, 1) BN1(r0.z, 2) BN1(r0.w, 3)
    BN1(r1.x, 4) BN1(r1.y, 5) BN1(r1.z, 6) BN1(r1.w, 7)
#undef BN1
    float4* orow = (float4*)(out + (idx >> 4) * C + c0);
    orow[0] = r0;
    orow[1] = r1;
}

extern "C" void kernel_launch(void* const* d_in, const int* in_sizes, int n_in,
                              void* d_out, int out_size, void* d_ws, size_t ws_size,
                              hipStream_t stream) {
    const float* x     = (const float*)d_in[0];
    const int*   ei    = (const int*)d_in[1];   // [2, E]: row = ei[e], col = ei[E+e]
    const float* ew    = (const float*)d_in[2];
    const float* W     = (const float*)d_in[3];
    const float* gamma = (const float*)d_in[4];
    const float* beta  = (const float*)d_in[5];

    const int n  = in_sizes[0] / C;
    const int nE = in_sizes[2];

    const int NB    = (n + 127) >> 7;          // 128-col buckets
    const int NBLK  = (nE + 8191) / 8192;      // hist/scatter blocks
    const int scanN = NB * NBLK;
    const int scanB = (scanN + 255) / 256;
    const int SB    = 256;                     // k_stats blocks

    float* out = (float*)d_out;
    char* p = (char*)d_ws;
#define ALLOC(TYPE, NAME, BYTES) \
    TYPE NAME = (TYPE)p; p += ((size_t)(BYTES) + 255) & ~(size_t)255;
    ALLOC(int2*,   ev2,    (size_t)nE * 8)
    ALLOC(ushort*, xb,     (size_t)n * C * 2)
    ALLOC(ushort*, aggb,   (size_t)n * C * 2)
    ALLOC(ushort*, outb,   (size_t)n * C * 2)
    ALLOC(int*,    counts, (size_t)scanN * 4)
    ALLOC(int*,    bsum,   (size_t)scanB * 4)
    ALLOC(float*,  dis,    (size_t)n * 4)
    ALLOC(ushort*, WbT,    32768)
    ALLOC(float*,  sums,   1024)
    ALLOC(float*,  part,   (size_t)SB * 256 * 4)
#undef ALLOC

    const long total4 = (long)n * 32;   // n*C/4 (f32 float4s)
    const long totalb = (long)n * 16;   // n*C/8 (bf16 uint4s)
    const int  cvtB   = (int)((total4 + 255) / 256);

    hipMemsetAsync(sums, 0, 256 * 4, stream);

    k_hist   <<<NBLK, 512, 0, stream>>>(ei + nE, counts, nE, NB, NBLK);
    k_scan1  <<<scanB, 256, 0, stream>>>(counts, bsum, scanN);
    k_scan2  <<<1, 256, 0, stream>>>(bsum, scanB);
    k_scatter<<<NBLK, 512, 0, stream>>>(ei, ew, counts, bsum, ev2, nE, NB, NBLK);
    k_deg    <<<NB, 256, 0, stream>>>(ev2, counts, bsum, dis, n, nE, NB, NBLK);
    k_cvt    <<<cvtB + 64, 256, 0, stream>>>((const float4*)x, dis, (ushort4*)xb, W, WbT, total4, cvtB);
    k_segagg <<<NB, 256, 0, stream>>>(xb, ev2, counts, bsum, dis, aggb, n, nE, NB, NBLK);
    k_gemm   <<<(n + 63) / 64, 256, 0, stream>>>(aggb, outb, WbT, n);
    k_stats  <<<SB, 1024, 0, stream>>>((const uint4*)outb, part, n);
    k_finish <<<16, 256, 0, stream>>>(part, sums, SB);
    k_apply  <<<(int)((totalb + 255) / 256), 256, 0, stream>>>((const uint4*)outb, out, sums, gamma, beta, n);
}